// Round 10
// baseline (194.315 us; speedup 1.0000x reference)
//
#include <hip/hip_runtime.h>
#include <cfloat>
#include <cmath>

#define MEM_DIM 2000
#define FEA     256
#define LAMBDA  0.0025f
#define HS_EPS  1e-12f

typedef unsigned short u16;
typedef unsigned int   u32;
typedef _Float16 f16x8  __attribute__((ext_vector_type(8)));
typedef float    f32x16 __attribute__((ext_vector_type(16)));

static const int Y_ELEMS = 16 * 256 * 1024;   // y output elements
static const int ATT_F4  = 8192000;           // att floats / 4

// workspace layout (float offsets), total 786432 floats = 3.0 MB:
//   [0 .. 524287]  : wsp u16[2][2048][256] (2 MB) while scores runs
//   [524288 .. 786431] : zp [16][16384] (1 MB) until k_zsum consumes it
//   AFTER those phases the regions are reused:
#define WS_Z    0        //   Z   [16384] full row sums
#define WS_DD   16384    //   dD  [16384] L1 denominators (atomic)
#define WS_CNT  32768    //   cnt [1024] bucket counters (u32; padded)
#define WS_BKT  49152    //   bkt [1024][360] uint2 = 737280 floats -> ends 786432
#define WS_ZP   524288   // zp (dead after k_zsum; overlapped by bkt tail)
#define BKT_CAP 360

// ---------------------------------------------------------------------------
// Kernel A: split x [16][256][1024] f32 -> xs planes [2][16][1024][256] f16
// ---------------------------------------------------------------------------
__global__ __launch_bounds__(256) void k_split_x(const float* __restrict__ x,
                                                 u16* __restrict__ xs) {
    __shared__ float tl[32][33];
    const int blk = blockIdx.x;           // 4096 = 16 b * 8 ct * 32 ht
    const int b   = blk >> 8;
    const int ct  = (blk >> 5) & 7;
    const int ht  = blk & 31;
    const int tx  = threadIdx.x & 31, ty = threadIdx.x >> 5;
#pragma unroll
    for (int i = 0; i < 4; ++i)
        tl[ty + 8 * i][tx] =
            x[(((b << 8) + (ct << 5) + ty + (i << 3)) << 10) + (ht << 5) + tx];
    __syncthreads();
#pragma unroll
    for (int i = 0; i < 4; ++i) {
        float v = tl[tx][ty + 8 * i];
        _Float16 a  = (_Float16)v;
        _Float16 bq = (_Float16)((v - (float)a) * 256.0f);
        const int hw = (ht << 5) + ty + (i << 3);
        const int c  = (ct << 5) + tx;
        const size_t o = (((size_t)(b << 10) + hw) << 8) + c;
        xs[o]           = *(u16*)&a;
        xs[4194304 + o] = *(u16*)&bq;
    }
}

// ---------------------------------------------------------------------------
// Kernel B: split W [2000][256] f32 -> wsp [2][2048][256] f16 (m zero-padded)
// ---------------------------------------------------------------------------
__global__ __launch_bounds__(256) void k_split_w(const float* __restrict__ W,
                                                 u16* __restrict__ wsp) {
    const int m = blockIdx.x;             // 2048
    const int c = threadIdx.x;
    float v = (m < MEM_DIM) ? W[(m << 8) + c] : 0.f;
    _Float16 a  = (_Float16)v;
    _Float16 bq = (_Float16)((v - (float)a) * 256.0f);
    wsp[(m << 8) + c]          = *(u16*)&a;
    wsp[524288 + (m << 8) + c] = *(u16*)&bq;
}

// ---------------------------------------------------------------------------
// Kernel 1: z = x.W^T via mfma_f32_32x32x16_f16, 2-split (3 passes, dual acc).
// EXACT round-9 version (bit-identical E): 48 KB dbuf, B1 in registers,
// 2-phase pipeline, direct float4 E-store epilogue.
// ---------------------------------------------------------------------------
__global__ __launch_bounds__(256) void k_scores_mfma(
    const u16* __restrict__ xs, const u16* __restrict__ wsp,
    float* __restrict__ S, float* __restrict__ zp) {
    __shared__ u16 lds[24576];   // 48 KB = 2 x 24 KB buffers
    const int t    = threadIdx.x;
    const int lane = t & 63;
    const int w    = t >> 6;
    const int wr   = w >> 1, wc = w & 1;
    const int lr   = lane & 31, lg = lane >> 5;

    const int bx  = blockIdx.x;
    const int wg  = ((bx & 7) << 8) | (bx >> 3);   // XCD swizzle (2048 = 8*256)
    const int m0t = wg & 15;
    const int rt  = wg >> 4;
    const int m0  = m0t << 7;
    const int b   = rt >> 3;
    const int hw0 = (rt & 7) << 7;

    const u16* gsrc[6];
#pragma unroll
    for (int i = 0; i < 6; ++i) {
        const int s = (i << 8) + t;
        const int tile = s >> 9;
        const int u = s & 511;
        const int r = u >> 2;
        const int cl = (u & 3) ^ ((r >> 1) & 3);
        if (tile < 2)
            gsrc[i] = xs + tile * 4194304 + (((b << 10) + hw0 + r) << 8) + (cl << 3);
        else
            gsrc[i] = wsp + ((m0 + r) << 8) + (cl << 3);
    }

    f32x16 acc1[2][2], acc2[2][2];
#pragma unroll
    for (int i = 0; i < 2; ++i)
#pragma unroll
        for (int j = 0; j < 2; ++j)
#pragma unroll
            for (int e = 0; e < 16; ++e) { acc1[i][j][e] = 0.f; acc2[i][j][e] = 0.f; }

    #define STAGE(kt, bufb)                                                          \
        {                                                                            \
            _Pragma("unroll")                                                        \
            for (int i = 0; i < 6; ++i) {                                            \
                const int s = (i << 8) + t;                                          \
                __builtin_amdgcn_global_load_lds(                                    \
                    (const __attribute__((address_space(1))) unsigned int*)(gsrc[i] + ((kt) << 5)), \
                    (__attribute__((address_space(3))) unsigned int*)&lds[(bufb) + (s << 3)],       \
                    16, 0, 0);                                                       \
            }                                                                        \
        }

    f16x8 b1c[2][2], b1n[2][2];
    #define LOADB1(dst, kt)                                                          \
        {                                                                            \
            _Pragma("unroll")                                                        \
            for (int mi = 0; mi < 2; ++mi)                                           \
                _Pragma("unroll")                                                    \
                for (int ks = 0; ks < 2; ++ks)                                       \
                    dst[mi][ks] = *(const f16x8*)&wsp[524288 +                       \
                        ((m0 + (wc << 6) + (mi << 5) + lr) << 8) + ((kt) << 5) +     \
                        (((ks << 1) + lg) << 3)];                                    \
        }

    #define COMPUTE(bufb)                                                            \
        {                                                                            \
            _Pragma("unroll")                                                        \
            for (int ks = 0; ks < 2; ++ks) {                                         \
                f16x8 a0[2], a1[2], b0[2];                                           \
                _Pragma("unroll")                                                    \
                for (int ri = 0; ri < 2; ++ri) {                                     \
                    const int R  = (wr << 6) + (ri << 5) + lr;                       \
                    const int pc = ((ks << 1) + lg) ^ ((R >> 1) & 3);                \
                    a0[ri] = *(const f16x8*)&lds[(bufb) +        (R << 5) + (pc << 3)]; \
                    a1[ri] = *(const f16x8*)&lds[(bufb) + 4096 + (R << 5) + (pc << 3)]; \
                }                                                                    \
                _Pragma("unroll")                                                    \
                for (int mi = 0; mi < 2; ++mi) {                                     \
                    const int M  = (wc << 6) + (mi << 5) + lr;                       \
                    const int pc = ((ks << 1) + lg) ^ ((M >> 1) & 3);                \
                    b0[mi] = *(const f16x8*)&lds[(bufb) + 8192 + (M << 5) + (pc << 3)]; \
                }                                                                    \
                _Pragma("unroll")                                                    \
                for (int ri = 0; ri < 2; ++ri)                                       \
                    _Pragma("unroll")                                                \
                    for (int mi = 0; mi < 2; ++mi) {                                 \
                        acc2[ri][mi] = __builtin_amdgcn_mfma_f32_32x32x16_f16(a0[ri], b1c[mi][ks], acc2[ri][mi], 0, 0, 0); \
                        acc2[ri][mi] = __builtin_amdgcn_mfma_f32_32x32x16_f16(a1[ri], b0[mi],      acc2[ri][mi], 0, 0, 0); \
                        acc1[ri][mi] = __builtin_amdgcn_mfma_f32_32x32x16_f16(a0[ri], b0[mi],      acc1[ri][mi], 0, 0, 0); \
                    }                                                                \
            }                                                                        \
        }

    STAGE(0, 0);
    LOADB1(b1c, 0);
    __syncthreads();
#pragma unroll
    for (int kt = 0; kt < 8; ++kt) {
        if (kt < 7) {
            STAGE(kt + 1, ((kt + 1) & 1) * 12288);
            LOADB1(b1n, kt + 1);
        }
        COMPUTE((kt & 1) * 12288);
        __syncthreads();
#pragma unroll
        for (int mi = 0; mi < 2; ++mi)
#pragma unroll
            for (int ks = 0; ks < 2; ++ks) b1c[mi][ks] = b1n[mi][ks];
    }
    #undef STAGE
    #undef LOADB1
    #undef COMPUTE

    float* zf = (float*)lds;

    float rs[2][16];
#pragma unroll
    for (int ri = 0; ri < 2; ++ri)
#pragma unroll
        for (int q = 0; q < 16; ++q) rs[ri][q] = 0.f;

#pragma unroll
    for (int ri = 0; ri < 2; ++ri)
#pragma unroll
        for (int mi = 0; mi < 2; ++mi) {
            const int m = m0 + (wc << 6) + (mi << 5) + lr;
            const bool valid = (m < MEM_DIM);
            float e[16];
#pragma unroll
            for (int q = 0; q < 16; ++q) {
                float z = acc1[ri][mi][q] + acc2[ri][mi][q] * 0.00390625f;
                e[q] = valid ? expf(z) : 0.f;
                rs[ri][q] += e[q];
            }
            if (valid) {
                const size_t pb = ((size_t)(b * MEM_DIM + m) << 10) + hw0
                                + (wr << 6) + (ri << 5) + (lg << 2);
#pragma unroll
                for (int q4 = 0; q4 < 4; ++q4) {
                    float4 v = {e[4 * q4], e[4 * q4 + 1], e[4 * q4 + 2], e[4 * q4 + 3]};
                    *(float4*)&S[pb + (q4 << 3)] = v;
                }
            }
        }

#pragma unroll
    for (int ri = 0; ri < 2; ++ri)
#pragma unroll
        for (int q = 0; q < 16; ++q) {
            float v = rs[ri][q];
            v += __shfl_xor(v, 1);
            v += __shfl_xor(v, 2);
            v += __shfl_xor(v, 4);
            v += __shfl_xor(v, 8);
            v += __shfl_xor(v, 16);
            rs[ri][q] = v;
        }
    if (lr == 0) {
#pragma unroll
        for (int ri = 0; ri < 2; ++ri)
#pragma unroll
            for (int q = 0; q < 16; ++q) {
                const int row = (wr << 6) + (ri << 5) + (q & 3) + ((q >> 2) << 3) + (lg << 2);
                zf[(wc << 7) + row] = rs[ri][q];
            }
    }
    __syncthreads();
    if (t < 128)
        zp[m0t * 16384 + (b << 10) + hw0 + t] = zf[t] + zf[128 + t];
}

// ---------------------------------------------------------------------------
// Kernel 2: Z = sum of 16 zp planes; zero dD and bucket counters.
// (must fully consume zp before k_pvD overwrites it with bucket entries)
// ---------------------------------------------------------------------------
__global__ __launch_bounds__(256) void k_zsum(const float* __restrict__ zp,
                                              float* __restrict__ Z,
                                              float* __restrict__ dD,
                                              u32* __restrict__ cnt) {
    const int i = blockIdx.x * 256 + threadIdx.x;   // 16384
    float z = 0.f;
#pragma unroll
    for (int mt = 0; mt < 16; ++mt) z += zp[mt * 16384 + i];
    Z[i] = z;
    dD[i] = 0.f;
    if (i < 1024) cnt[i] = 0;
}

// ---------------------------------------------------------------------------
// Kernel 3: single E-consumer. Coalesced panel streaming: computes D partials
// (atomicAdd into dD) AND appends survivors (m, hw, s) to hw-chunk buckets.
// Survivor predicate d > 0 is exactly the reference's nonzero-ness.
// ---------------------------------------------------------------------------
__global__ __launch_bounds__(256) void k_pvD(const float* __restrict__ att,
                                             const float* __restrict__ Z,
                                             float* __restrict__ dD,
                                             u32* __restrict__ cnt,
                                             uint2* __restrict__ bkt) {
    const int blk = blockIdx.x;          // 2000 = 16 b x 125 panel-groups
    const int b   = blk / 125;
    const int mg  = blk % 125;
    const int hw  = threadIdx.x << 2;
    float4 Z4 = *(const float4*)&Z[(b << 10) + hw];
    const float4 rZ = {1.f / Z4.x, 1.f / Z4.y, 1.f / Z4.z, 1.f / Z4.w};
    const size_t pb = ((size_t)(b * MEM_DIM + mg * 16) << 10) + hw;

    float4 D = {0.f, 0.f, 0.f, 0.f};
#pragma unroll
    for (int i = 0; i < 16; ++i) {
        const int m = mg * 16 + i;
        float4 e = *(const float4*)&att[pb + ((size_t)i << 10)];
        float sv[4];
        { float a = e.x * rZ.x, d = a - LAMBDA; sv[0] = fmaxf(d, 0.f) * a / (fabsf(d) + HS_EPS); D.x += sv[0]; }
        { float a = e.y * rZ.y, d = a - LAMBDA; sv[1] = fmaxf(d, 0.f) * a / (fabsf(d) + HS_EPS); D.y += sv[1]; }
        { float a = e.z * rZ.z, d = a - LAMBDA; sv[2] = fmaxf(d, 0.f) * a / (fabsf(d) + HS_EPS); D.z += sv[2]; }
        { float a = e.w * rZ.w, d = a - LAMBDA; sv[3] = fmaxf(d, 0.f) * a / (fabsf(d) + HS_EPS); D.w += sv[3]; }
#pragma unroll
        for (int c = 0; c < 4; ++c) {
            if (sv[c] > 0.f) {
                const int hwc = hw + c;
                const int ch  = (b << 6) + (hwc >> 4);
                u32 idx = atomicAdd(&cnt[ch], 1u);
                if (idx < (u32)BKT_CAP)
                    bkt[ch * BKT_CAP + idx] =
                        make_uint2((u32)(mg * 16 + i) | ((u32)(hwc & 15) << 16),
                                   __float_as_uint(sv[c]));
            }
        }
    }
    float* dp = &dD[(b << 10) + hw];
    atomicAdd(&dp[0], D.x);
    atomicAdd(&dp[1], D.y);
    atomicAdd(&dp[2], D.z);
    atomicAdd(&dp[3], D.w);
}

// ---------------------------------------------------------------------------
// Kernel 4: streaming zero-fill of the att region (write-only).
// ---------------------------------------------------------------------------
__global__ __launch_bounds__(256) void k_zero(float4* __restrict__ att4) {
    const float4 z = {0.f, 0.f, 0.f, 0.f};
    for (int i = blockIdx.x * 256 + threadIdx.x; i < ATT_F4; i += 2048 * 256)
        att4[i] = z;
}

// ---------------------------------------------------------------------------
// Kernel 5: per hw-chunk: scatter att survivors (s*rD) and build y.
// ---------------------------------------------------------------------------
__global__ __launch_bounds__(256) void k_y(const float* __restrict__ W,
                                           const u32* __restrict__ cnt,
                                           const uint2* __restrict__ bkt,
                                           const float* __restrict__ dD,
                                           float* __restrict__ att,
                                           float* __restrict__ y) {
    __shared__ float ylds[16][257];
    __shared__ float rDsh[16];
    const int ch  = blockIdx.x;           // 1024
    const int b   = ch >> 6;
    const int hw0 = (ch & 63) << 4;
    const int t   = threadIdx.x;

    for (int i = t; i < 16 * 257; i += 256) ((float*)ylds)[i] = 0.f;
    if (t < 16) rDsh[t] = 1.f / fmaxf(dD[(b << 10) + hw0 + t], HS_EPS);
    __syncthreads();

    const int n = min((int)cnt[ch], BKT_CAP);

    // scatter normalized survivors into att (zero-filled by k_zero)
    for (int i = t; i < n; i += 256) {
        uint2 e = bkt[ch * BKT_CAP + i];
        const int m = e.x & 0xFFFF;
        const int r = e.x >> 16;
        att[((size_t)(b * MEM_DIM + m) << 10) + hw0 + r] =
            __uint_as_float(e.y) * rDsh[r];
    }

    // accumulate y: thread owns column t
    for (int i = 0; i < n; ++i) {
        uint2 e = bkt[ch * BKT_CAP + i];
        const int m = e.x & 0xFFFF;
        const int r = e.x >> 16;
        const float v = __uint_as_float(e.y) * rDsh[r];
        ylds[r][t] += v * W[(m << 8) + t];
    }
    __syncthreads();

#pragma unroll
    for (int it = 0; it < 16; ++it) {
        const int cc = (it << 4) + (t >> 4);
        const int r  = t & 15;
        y[(((b << 8) + cc) << 10) + hw0 + r] = ylds[r][cc];
    }
}

// ---------------------------------------------------------------------------
extern "C" void kernel_launch(void* const* d_in, const int* in_sizes, int n_in,
                              void* d_out, int out_size, void* d_ws, size_t ws_size,
                              hipStream_t stream) {
    const float* x = (const float*)d_in[0];
    const float* W = (const float*)d_in[1];
    float* out = (float*)d_out;
    float* y   = out;
    float* att = out + (size_t)Y_ELEMS;
    float* wsf = (float*)d_ws;
    u16*   wsp = (u16*)d_ws;                 // 2 MB, dead after k_scores_mfma
    float* Z   = wsf + WS_Z;                 // reuses wsp region
    float* dD  = wsf + WS_DD;                // reuses wsp region
    u32*   cnt = (u32*)(wsf + WS_CNT);       // reuses wsp region
    uint2* bkt = (uint2*)(wsf + WS_BKT);     // reuses wsp tail + dead zp region
    float* zp  = wsf + WS_ZP;                // dead after k_zsum
    u16*   xs  = (u16*)y;                    // 16.8 MB staging in y region
                                             // (consumed before k_y writes y)

    k_split_x    <<<4096, 256, 0, stream>>>(x, xs);
    k_split_w    <<<2048, 256, 0, stream>>>(W, wsp);
    k_scores_mfma<<<2048, 256, 0, stream>>>(xs, wsp, att, zp);
    k_zsum       <<<64,   256, 0, stream>>>(zp, Z, dD, cnt);
    k_pvD        <<<2000, 256, 0, stream>>>(att, Z, dD, cnt, bkt);
    k_zero       <<<2048, 256, 0, stream>>>((float4*)att);
    k_y          <<<1024, 256, 0, stream>>>(W, cnt, bkt, dD, att, y);
}

// Round 11
// 186.205 us; speedup vs baseline: 1.0436x; 1.0436x over previous
//
#include <hip/hip_runtime.h>
#include <cfloat>
#include <cmath>

#define MEM_DIM 2000
#define FEA     256
#define LAMBDA  0.0025f
#define HS_EPS  1e-12f

typedef unsigned short u16;
typedef unsigned int   u32;
typedef _Float16 f16x8  __attribute__((ext_vector_type(8)));
typedef float    f32x16 __attribute__((ext_vector_type(16)));

static const int Y_ELEMS = 16 * 256 * 1024;   // y output elements

// workspace layout (float offsets), total 786432 floats = 3.0 MB:
//   [0 .. 524287]   : wsp u16[2][2048][256] (2 MB) while scores runs;
//                     AFTER k_scores this region is reused:
#define WS_Z    0        //   Z   [16384] full row sums
#define WS_DD   16384    //   dD  [16384] L1 denominators (atomic)
#define WS_CNT  32768    //   cnt [1024] bucket counters (u32; padded)
#define WS_BKT  49152    //   bkt [1024][224] uint2 = 458752 floats (ends 507904)
#define WS_ZP   524288   // zp [16][16384] partial sum(e^z) per m-tile (1 MB)
#define BKT_CAP 224

// ---------------------------------------------------------------------------
// Kernel A: split x [16][256][1024] f32 -> xs planes [2][16][1024][256] f16
// ---------------------------------------------------------------------------
__global__ __launch_bounds__(256) void k_split_x(const float* __restrict__ x,
                                                 u16* __restrict__ xs) {
    __shared__ float tl[32][33];
    const int blk = blockIdx.x;           // 4096 = 16 b * 8 ct * 32 ht
    const int b   = blk >> 8;
    const int ct  = (blk >> 5) & 7;
    const int ht  = blk & 31;
    const int tx  = threadIdx.x & 31, ty = threadIdx.x >> 5;
#pragma unroll
    for (int i = 0; i < 4; ++i)
        tl[ty + 8 * i][tx] =
            x[(((b << 8) + (ct << 5) + ty + (i << 3)) << 10) + (ht << 5) + tx];
    __syncthreads();
#pragma unroll
    for (int i = 0; i < 4; ++i) {
        float v = tl[tx][ty + 8 * i];
        _Float16 a  = (_Float16)v;
        _Float16 bq = (_Float16)((v - (float)a) * 256.0f);
        const int hw = (ht << 5) + ty + (i << 3);
        const int c  = (ct << 5) + tx;
        const size_t o = (((size_t)(b << 10) + hw) << 8) + c;
        xs[o]           = *(u16*)&a;
        xs[4194304 + o] = *(u16*)&bq;
    }
}

// ---------------------------------------------------------------------------
// Kernel B: split W [2000][256] f32 -> wsp [2][2048][256] f16 (m zero-padded)
// ---------------------------------------------------------------------------
__global__ __launch_bounds__(256) void k_split_w(const float* __restrict__ W,
                                                 u16* __restrict__ wsp) {
    const int m = blockIdx.x;             // 2048
    const int c = threadIdx.x;
    float v = (m < MEM_DIM) ? W[(m << 8) + c] : 0.f;
    _Float16 a  = (_Float16)v;
    _Float16 bq = (_Float16)((v - (float)a) * 256.0f);
    wsp[(m << 8) + c]          = *(u16*)&a;
    wsp[524288 + (m << 8) + c] = *(u16*)&bq;
}

// ---------------------------------------------------------------------------
// Kernel 1: z = x.W^T via mfma_f32_32x32x16_f16, 2-split (3 passes, dual acc).
// EXACT round-5 version (fastest measured: ~85 us, MfmaUtil 26.5%):
// 64 KB LDS = 2 x 32 KB buffers {A0,A1,B0,B1}, 8-load STAGE, 2-phase
// pipeline, 2-way chunk swizzle, direct float4 E-store epilogue.
// ---------------------------------------------------------------------------
__global__ __launch_bounds__(256) void k_scores_mfma(
    const u16* __restrict__ xs, const u16* __restrict__ wsp,
    float* __restrict__ S, float* __restrict__ zp) {
    __shared__ u16 lds[32768];   // 64 KB = 2 x 32 KB buffers
    const int t    = threadIdx.x;
    const int lane = t & 63;
    const int w    = t >> 6;
    const int wr   = w >> 1, wc = w & 1;
    const int lr   = lane & 31, lg = lane >> 5;

    const int bx  = blockIdx.x;
    const int wg  = ((bx & 7) << 8) | (bx >> 3);   // XCD swizzle (2048 = 8*256)
    const int m0t = wg & 15;
    const int rt  = wg >> 4;
    const int m0  = m0t << 7;
    const int b   = rt >> 3;
    const int hw0 = (rt & 7) << 7;

    // staging: 8 issues x 256 thr x 16 B = 32 KB/buffer. slot s -> tile(s>>9),
    // row r=(s&511)>>2, phys chunk cp=s&3 holds logical chunk cp^((r>>1)&3).
    const u16* gsrc[8];
#pragma unroll
    for (int i = 0; i < 8; ++i) {
        const int s = (i << 8) + t;
        const int tile = s >> 9;
        const int u = s & 511;
        const int r = u >> 2;
        const int cl = (u & 3) ^ ((r >> 1) & 3);
        if (tile < 2)
            gsrc[i] = xs + tile * 4194304 + (((b << 10) + hw0 + r) << 8) + (cl << 3);
        else
            gsrc[i] = wsp + ((tile - 2) << 19) + ((m0 + r) << 8) + (cl << 3);
    }

    f32x16 acc1[2][2], acc2[2][2];
#pragma unroll
    for (int i = 0; i < 2; ++i)
#pragma unroll
        for (int j = 0; j < 2; ++j)
#pragma unroll
            for (int e = 0; e < 16; ++e) { acc1[i][j][e] = 0.f; acc2[i][j][e] = 0.f; }

    #define STAGE(kt, bufb)                                                          \
        {                                                                            \
            _Pragma("unroll")                                                        \
            for (int i = 0; i < 8; ++i) {                                            \
                const int s = (i << 8) + t;                                          \
                __builtin_amdgcn_global_load_lds(                                    \
                    (const __attribute__((address_space(1))) unsigned int*)(gsrc[i] + ((kt) << 5)), \
                    (__attribute__((address_space(3))) unsigned int*)&lds[(bufb) + (s << 3)],       \
                    16, 0, 0);                                                       \
            }                                                                        \
        }

    #define COMPUTE(bufb)                                                            \
        {                                                                            \
            _Pragma("unroll")                                                        \
            for (int ks = 0; ks < 2; ++ks) {                                         \
                f16x8 a0[2], a1[2], b0[2], b1[2];                                    \
                _Pragma("unroll")                                                    \
                for (int ri = 0; ri < 2; ++ri) {                                     \
                    const int R  = (wr << 6) + (ri << 5) + lr;                       \
                    const int pc = ((ks << 1) + lg) ^ ((R >> 1) & 3);                \
                    a0[ri] = *(const f16x8*)&lds[(bufb) +        (R << 5) + (pc << 3)]; \
                    a1[ri] = *(const f16x8*)&lds[(bufb) + 4096 + (R << 5) + (pc << 3)]; \
                }                                                                    \
                _Pragma("unroll")                                                    \
                for (int mi = 0; mi < 2; ++mi) {                                     \
                    const int M  = (wc << 6) + (mi << 5) + lr;                       \
                    const int pc = ((ks << 1) + lg) ^ ((M >> 1) & 3);                \
                    b0[mi] = *(const f16x8*)&lds[(bufb) +  8192 + (M << 5) + (pc << 3)]; \
                    b1[mi] = *(const f16x8*)&lds[(bufb) + 12288 + (M << 5) + (pc << 3)]; \
                }                                                                    \
                _Pragma("unroll")                                                    \
                for (int ri = 0; ri < 2; ++ri)                                       \
                    _Pragma("unroll")                                                \
                    for (int mi = 0; mi < 2; ++mi) {                                 \
                        acc2[ri][mi] = __builtin_amdgcn_mfma_f32_32x32x16_f16(a0[ri], b1[mi], acc2[ri][mi], 0, 0, 0); \
                        acc2[ri][mi] = __builtin_amdgcn_mfma_f32_32x32x16_f16(a1[ri], b0[mi], acc2[ri][mi], 0, 0, 0); \
                        acc1[ri][mi] = __builtin_amdgcn_mfma_f32_32x32x16_f16(a0[ri], b0[mi], acc1[ri][mi], 0, 0, 0); \
                    }                                                                \
            }                                                                        \
        }

    STAGE(0, 0);
    __syncthreads();
#pragma unroll
    for (int kt = 0; kt < 8; ++kt) {
        if (kt < 7) STAGE(kt + 1, ((kt + 1) & 1) << 14);
        COMPUTE((kt & 1) << 14);
        __syncthreads();
    }
    #undef STAGE
    #undef COMPUTE

    float* zf = (float*)lds;

    float rs[2][16];
#pragma unroll
    for (int ri = 0; ri < 2; ++ri)
#pragma unroll
        for (int q = 0; q < 16; ++q) rs[ri][q] = 0.f;

#pragma unroll
    for (int ri = 0; ri < 2; ++ri)
#pragma unroll
        for (int mi = 0; mi < 2; ++mi) {
            const int m = m0 + (wc << 6) + (mi << 5) + lr;
            const bool valid = (m < MEM_DIM);
            float e[16];
#pragma unroll
            for (int q = 0; q < 16; ++q) {
                float z = acc1[ri][mi][q] + acc2[ri][mi][q] * 0.00390625f;
                e[q] = valid ? expf(z) : 0.f;
                rs[ri][q] += e[q];
            }
            if (valid) {
                const size_t pb = ((size_t)(b * MEM_DIM + m) << 10) + hw0
                                + (wr << 6) + (ri << 5) + (lg << 2);
#pragma unroll
                for (int q4 = 0; q4 < 4; ++q4) {
                    float4 v = {e[4 * q4], e[4 * q4 + 1], e[4 * q4 + 2], e[4 * q4 + 3]};
                    *(float4*)&S[pb + (q4 << 3)] = v;
                }
            }
        }

#pragma unroll
    for (int ri = 0; ri < 2; ++ri)
#pragma unroll
        for (int q = 0; q < 16; ++q) {
            float v = rs[ri][q];
            v += __shfl_xor(v, 1);
            v += __shfl_xor(v, 2);
            v += __shfl_xor(v, 4);
            v += __shfl_xor(v, 8);
            v += __shfl_xor(v, 16);
            rs[ri][q] = v;
        }
    if (lr == 0) {
#pragma unroll
        for (int ri = 0; ri < 2; ++ri)
#pragma unroll
            for (int q = 0; q < 16; ++q) {
                const int row = (wr << 6) + (ri << 5) + (q & 3) + ((q >> 2) << 3) + (lg << 2);
                zf[(wc << 7) + row] = rs[ri][q];
            }
    }
    __syncthreads();
    if (t < 128)
        zp[m0t * 16384 + (b << 10) + hw0 + t] = zf[t] + zf[128 + t];
}

// ---------------------------------------------------------------------------
// Kernel 2: Z = sum of 16 zp planes; zero dD and bucket counters.
// ---------------------------------------------------------------------------
__global__ __launch_bounds__(256) void k_zsum(const float* __restrict__ zp,
                                              float* __restrict__ Z,
                                              float* __restrict__ dD,
                                              u32* __restrict__ cnt) {
    const int i = blockIdx.x * 256 + threadIdx.x;   // 16384
    float z = 0.f;
#pragma unroll
    for (int mt = 0; mt < 16; ++mt) z += zp[mt * 16384 + i];
    Z[i] = z;
    dD[i] = 0.f;
    if (i < 1024) cnt[i] = 0;
}

// ---------------------------------------------------------------------------
// Kernel 3: D-reduction. Block = (b, 125 m-panel-groups); thread = float4 of
// hw. Coalesced panel streaming; one atomicAdd per element at the end.
// ---------------------------------------------------------------------------
__global__ __launch_bounds__(256) void k_pvD(const float* __restrict__ att,
                                             const float* __restrict__ Z,
                                             float* __restrict__ dD) {
    const int blk = blockIdx.x;          // 2000 = 16 b x 125 panel-groups
    const int b   = blk / 125;
    const int mg  = blk % 125;
    const int hw  = threadIdx.x << 2;
    float4 Z4 = *(const float4*)&Z[(b << 10) + hw];
    const float4 rZ = {1.f / Z4.x, 1.f / Z4.y, 1.f / Z4.z, 1.f / Z4.w};
    const size_t pb = ((size_t)(b * MEM_DIM + mg * 16) << 10) + hw;

    float4 D = {0.f, 0.f, 0.f, 0.f};
#pragma unroll
    for (int i = 0; i < 16; ++i) {
        float4 e = *(const float4*)&att[pb + ((size_t)i << 10)];
        { float a = e.x * rZ.x, d = a - LAMBDA; D.x += fmaxf(d, 0.f) * a / (fabsf(d) + HS_EPS); }
        { float a = e.y * rZ.y, d = a - LAMBDA; D.y += fmaxf(d, 0.f) * a / (fabsf(d) + HS_EPS); }
        { float a = e.z * rZ.z, d = a - LAMBDA; D.z += fmaxf(d, 0.f) * a / (fabsf(d) + HS_EPS); }
        { float a = e.w * rZ.w, d = a - LAMBDA; D.w += fmaxf(d, 0.f) * a / (fabsf(d) + HS_EPS); }
    }
    float* dp = &dD[(b << 10) + hw];
    atomicAdd(&dp[0], D.x);
    atomicAdd(&dp[1], D.y);
    atomicAdd(&dp[2], D.z);
    atomicAdd(&dp[3], D.w);
}

// ---------------------------------------------------------------------------
// Kernel 4: final att = s*rD written in place (coalesced panel streaming);
// survivors appended to per-row-chunk buckets for k_y.
// ---------------------------------------------------------------------------
__global__ __launch_bounds__(256) void k_pv_att(float* __restrict__ att,
                                                const float* __restrict__ Z,
                                                const float* __restrict__ dD,
                                                u32* __restrict__ cnt,
                                                uint2* __restrict__ bkt) {
    const int blk = blockIdx.x;          // 2000 = 16 b x 125 panel-groups
    const int b   = blk / 125;
    const int mg  = blk % 125;
    const int hw  = threadIdx.x << 2;
    float4 Z4 = *(const float4*)&Z[(b << 10) + hw];
    const float4 rZ = {1.f / Z4.x, 1.f / Z4.y, 1.f / Z4.z, 1.f / Z4.w};
    float4 D4 = *(const float4*)&dD[(b << 10) + hw];
    const float4 rD = {1.f / fmaxf(D4.x, HS_EPS), 1.f / fmaxf(D4.y, HS_EPS),
                       1.f / fmaxf(D4.z, HS_EPS), 1.f / fmaxf(D4.w, HS_EPS)};
    const size_t pb = ((size_t)(b * MEM_DIM + mg * 16) << 10) + hw;

#pragma unroll 4
    for (int i = 0; i < 16; ++i) {
        const int m = mg * 16 + i;
        float4 e = *(const float4*)&att[pb + ((size_t)i << 10)];
        float4 v;
        { float a = e.x * rZ.x, d = a - LAMBDA; v.x = fmaxf(d, 0.f) * a / (fabsf(d) + HS_EPS) * rD.x; }
        { float a = e.y * rZ.y, d = a - LAMBDA; v.y = fmaxf(d, 0.f) * a / (fabsf(d) + HS_EPS) * rD.y; }
        { float a = e.z * rZ.z, d = a - LAMBDA; v.z = fmaxf(d, 0.f) * a / (fabsf(d) + HS_EPS) * rD.z; }
        { float a = e.w * rZ.w, d = a - LAMBDA; v.w = fmaxf(d, 0.f) * a / (fabsf(d) + HS_EPS) * rD.w; }
        *(float4*)&att[pb + ((size_t)i << 10)] = v;

        const float vv[4] = {v.x, v.y, v.z, v.w};
#pragma unroll
        for (int c = 0; c < 4; ++c) {
            if (vv[c] != 0.f) {
                const int hwc = hw + c;
                const int ch  = (b << 6) + (hwc >> 4);
                u32 idx = atomicAdd(&cnt[ch], 1u);
                if (idx < BKT_CAP)
                    bkt[ch * BKT_CAP + idx] =
                        make_uint2((u32)m | ((u32)(hwc & 15) << 16), __float_as_uint(vv[c]));
            }
        }
    }
}

// ---------------------------------------------------------------------------
// Kernel 5: y from survivor buckets. Block = one 16-row chunk; thread = c.
// ~33 entries/block avg, no atomics on the fast path. If a chunk overflowed
// its bucket (rare), dense-scan fallback over the final att.
// ---------------------------------------------------------------------------
__global__ __launch_bounds__(256) void k_y(const float* __restrict__ W,
                                           const u32* __restrict__ cnt,
                                           const uint2* __restrict__ bkt,
                                           const float* __restrict__ att,
                                           float* __restrict__ y) {
    __shared__ float ylds[16][257];
    const int ch  = blockIdx.x;           // 1024
    const int b   = ch >> 6;
    const int hw0 = (ch & 63) << 4;
    const int t   = threadIdx.x;

    for (int i = t; i < 16 * 257; i += 256) ((float*)ylds)[i] = 0.f;
    __syncthreads();

    const u32 n_raw = cnt[ch];
    if (n_raw <= (u32)BKT_CAP) {
        const int n = (int)n_raw;
        for (int i = 0; i < n; ++i) {
            uint2 e = bkt[ch * BKT_CAP + i];
            const int m  = e.x & 0xFFFF;
            const int r4 = e.x >> 16;
            const float v = __uint_as_float(e.y);
            ylds[r4][t] += v * W[(m << 8) + t];
        }
    } else {
        // dense fallback: thread (mo, r) scans m = mo mod 16 for row r
        const int r  = t & 15;
        const int mo = t >> 4;
        for (int m = mo; m < MEM_DIM; m += 16) {
            float a = att[((size_t)(b * MEM_DIM + m) << 10) + hw0 + r];
            if (a != 0.f) {
                for (int c = 0; c < 256; ++c)
                    atomicAdd(&ylds[r][c], a * W[(m << 8) + c]);
            }
        }
    }
    __syncthreads();

#pragma unroll
    for (int it = 0; it < 16; ++it) {
        const int cc = (it << 4) + (t >> 4);
        const int r  = t & 15;
        y[(((b << 8) + cc) << 10) + hw0 + r] = ylds[r][cc];
    }
}

// ---------------------------------------------------------------------------
extern "C" void kernel_launch(void* const* d_in, const int* in_sizes, int n_in,
                              void* d_out, int out_size, void* d_ws, size_t ws_size,
                              hipStream_t stream) {
    const float* x = (const float*)d_in[0];
    const float* W = (const float*)d_in[1];
    float* out = (float*)d_out;
    float* y   = out;
    float* att = out + (size_t)Y_ELEMS;
    float* wsf = (float*)d_ws;
    u16*   wsp = (u16*)d_ws;                 // 2 MB, dead after k_scores_mfma
    float* Z   = wsf + WS_Z;                 // reuses wsp region
    float* dD  = wsf + WS_DD;                // reuses wsp region
    u32*   cnt = (u32*)(wsf + WS_CNT);       // reuses wsp region
    uint2* bkt = (uint2*)(wsf + WS_BKT);     // reuses wsp region
    float* zp  = wsf + WS_ZP;
    u16*   xs  = (u16*)y;                    // 16.8 MB staging in y region
                                             // (consumed before k_y writes y)

    k_split_x    <<<4096, 256, 0, stream>>>(x, xs);
    k_split_w    <<<2048, 256, 0, stream>>>(W, wsp);
    k_scores_mfma<<<2048, 256, 0, stream>>>(xs, wsp, att, zp);
    k_zsum       <<<64,   256, 0, stream>>>(zp, Z, dD, cnt);
    k_pvD        <<<2000, 256, 0, stream>>>(att, Z, dD);
    k_pv_att     <<<2000, 256, 0, stream>>>(att, Z, dD, cnt, bkt);
    k_y          <<<1024, 256, 0, stream>>>(W, cnt, bkt, att, y);
}